// Round 12
// baseline (56.517 us; speedup 1.0000x reference)
//
#include <hip/hip_runtime.h>
#include <math.h>

#define MASK_THR 0.53f
#define NBLKA 512       // binA blocks
#define BLKA_THR 1024   // binA threads/block (64KB slab -> 2 blk/CU)
#define BFIN_THR 1024   // binBfin threads/block
#define CAPB 32         // slots per (block,bucket) slab cell
#define NBK 256         // max buckets
#define BSH 12          // bins per bucket = 4096
#define BMSK 4095
#define OVFC 64         // per-block overflow cap
#define DEGCAP 64       // CSR cap per node

typedef unsigned long long u64;

// ---- binA: single pass, LDS slabs, zero global atomics, fused CSR build. --
// Packing: p in [0.53,1) => exponent fixed 126 => mantissa orders as p.
// Output needs only winner's instance n => val=(mant<<9)|(NB1-n):
// max val = max p, tie -> min n. val always nonzero for candidates => an
// all-zero slab slot merges as atomicMax(bins[0],0) == no-op, so the dump
// and merge are UNCONDITIONAL (no counts, pure streaming).
// buf layout is BUCKET-MAJOR: buf[bucket][block][slot] -> binBfin reads one
// contiguous 131KB region per block.
__global__ __launch_bounds__(BLKA_THR) void k_binA(
        const float* __restrict__ prob, const int* __restrict__ coords,
        const float* __restrict__ adj,
        u64* __restrict__ buf,
        unsigned* __restrict__ ovfcnt, u64* __restrict__ ovf,
        unsigned* __restrict__ deg, int* __restrict__ cols,
        int NE, int HW4, int NB1, const int* __restrict__ d_size1,
        int i4PerBlk, int N) {
    __shared__ u64 slab[NBK * CAPB];     // 64 KB
    __shared__ unsigned hist[NBK];
    __shared__ unsigned lcnt, ocnt;
    int tid = threadIdx.x, blk = blockIdx.x;
    for (int i = tid; i < NBK; i += BLKA_THR) hist[i] = 0u;
    for (int i = tid; i < NBK * CAPB; i += BLKA_THR) slab[i] = 0ull;
    if (tid == 0) { lcnt = 0u; ocnt = 0u; }
    __syncthreads();
    // fused CSR build: block blk scans adjacency row blk (order-free: the
    // walk sums are exact integer fp32 adds => commutative).
    if (blk < N) {
        for (int c = tid; c < N; c += BLKA_THR)
            if (adj[(size_t)blk * N + c] != 0.0f) {
                unsigned pos = atomicAdd(&lcnt, 1u);
                if (pos < DEGCAP) cols[(size_t)blk * DEGCAP + pos] = c;
            }
    }
    // scatter into LDS slab
    int size1 = *d_size1;
    int NE4 = NE >> 2;
    int i4Base = blk * i4PerBlk;
    int i4End = min(i4Base + i4PerBlk, NE4);
    for (int i4 = i4Base + tid; i4 < i4End; i4 += BLKA_THR) {
        float4 p = ((const float4*)prob)[i4];
        float pv[4] = {p.x, p.y, p.z, p.w};
        bool any = (pv[0] >= MASK_THR) | (pv[1] >= MASK_THR) |
                   (pv[2] >= MASK_THR) | (pv[3] >= MASK_THR);
        if (!any) continue;   // skip coord loads when the whole group fails
        int4 x = ((const int4*)coords)[i4];
        int4 y = ((const int4*)(coords + NE))[i4];
        unsigned n = (unsigned)i4 / (unsigned)HW4;   // HW%4==0: 4 px share n
        unsigned tie = (unsigned)(NB1 - (int)n);
        int   xv[4] = {x.x, x.y, x.z, x.w};
        int   yv[4] = {y.x, y.y, y.z, y.w};
#pragma unroll
        for (int e = 0; e < 4; ++e)
            if (pv[e] >= MASK_THR) {
                unsigned key = (unsigned)(xv[e] * size1 + yv[e]);
                unsigned b = key >> BSH;
                unsigned v = ((__float_as_uint(pv[e]) & 0x7FFFFFu) << 9) | tie;
                unsigned pos = atomicAdd(&hist[b], 1u);
                if (pos < CAPB)
                    slab[b * CAPB + pos] = ((u64)(key & BMSK) << 32) | v;
                else {
                    unsigned g = atomicAdd(&ocnt, 1u);
                    if (g < OVFC) ovf[(size_t)blk * OVFC + g] =
                        ((u64)key << 32) | v;
                }
            }
    }
    __syncthreads();
    if (tid == 0) {
        ovfcnt[blk] = min(ocnt, (unsigned)OVFC);
        if (blk < N) deg[blk] = min(lcnt, (unsigned)DEGCAP);
    }
    // unconditional dump, bucket-major: per bucket a 256B contiguous segment
    // at buf[(b*NBLKA + blk)*CAPB]. Threads tid..tid+31 share one segment.
    for (int j = tid; j < NBK * CAPB; j += BLKA_THR) {
        int b = j >> 5, s = j & (CAPB - 1);
        buf[((size_t)b * NBLKA + blk) * CAPB + s] = slab[j];
    }
}

// ---- k_walk: one block per node. v <- (I+A) v, 10 times, in LDS; then
// remap[i] = 1 + max({i} U {j != i : v[j] > 1}). Exactness: all counts are
// nonneg integers; 0/1 entries are sums of tiny exact terms (exact in fp32
// in both this and the reference's matmuls); entries >= 2 can round but
// never below the >1 threshold => classification identical to reference. ----
__global__ __launch_bounds__(256) void k_walk(
        const unsigned* __restrict__ deg, const int* __restrict__ cols,
        float* __restrict__ rmap, int N) {
    __shared__ float v0[512], v1[512];
    __shared__ int red[4];
    int i = blockIdx.x, tid = threadIdx.x;
    for (int j = tid; j < N; j += 256) v0[j] = (j == i) ? 1.0f : 0.0f;
    __syncthreads();
    float* cur = v0; float* nxt = v1;
    for (int it = 0; it < 10; ++it) {
        for (int j = tid; j < N; j += 256) {
            float s = cur[j];
            unsigned d = deg[j];
            const int* cj = cols + (size_t)j * DEGCAP;
            for (unsigned k = 0; k < d; ++k) s += cur[cj[k]];
            nxt[j] = s;
        }
        __syncthreads();
        float* t = cur; cur = nxt; nxt = t;
    }
    int best = i;
    for (int j = tid; j < N; j += 256)
        if (j != i && cur[j] > 1.0f && j > best) best = j;
    for (int off = 32; off; off >>= 1) {
        int o = __shfl_down(best, off);
        if (o > best) best = o;
    }
    if ((tid & 63) == 0) red[tid >> 6] = best;
    __syncthreads();
    if (tid == 0) {
        for (int w = 1; w < 4; ++w) if (red[w] > best) best = red[w];
        rmap[i] = (float)(best + 1);
    }
}

// ---- binBfin: block b streams its contiguous 131KB bucket region (key in
// high dword, val in low dword; zero slots are no-ops), LDS-atomicMax merge,
// then overflow, then write output segment [b<<BSH,(b+1)<<BSH) via rmap. ----
__global__ __launch_bounds__(BFIN_THR) void k_binBfin(
        const u64* __restrict__ buf,
        const unsigned* __restrict__ ovfcnt, const u64* __restrict__ ovf,
        const float* __restrict__ rmap, float* __restrict__ out,
        int total, int NB1) {
    __shared__ unsigned bins[1 << BSH];  // 16 KB
    __shared__ unsigned oc[NBLKA];       // 2 KB
    int b = blockIdx.x, tid = threadIdx.x;
    for (int i = tid; i < (1 << BSH); i += BFIN_THR) bins[i] = 0u;
    for (int s = tid; s < NBLKA; s += BFIN_THR) oc[s] = ovfcnt[s];
    __syncthreads();
    // contiguous stream: NBLKA*CAPB u64 = 8192 uint4
    const uint4* src = (const uint4*)(buf + (size_t)b * NBLKA * CAPB);
    const int n4 = NBLKA * CAPB / 2;
    for (int j = tid; j < n4; j += BFIN_THR) {
        uint4 u = src[j];
        atomicMax(&bins[u.y], u.x);   // key=high dword (<=BMSK), val=low
        atomicMax(&bins[u.w], u.z);
    }
    for (int j = tid; j < NBLKA * OVFC; j += BFIN_THR) {
        int s = j / OVFC, e = j % OVFC;
        if (e < (int)oc[s]) {
            u64 kv = ovf[(size_t)s * OVFC + e];
            unsigned key = (unsigned)(kv >> 32);
            if ((int)(key >> BSH) == b)
                atomicMax(&bins[key & BMSK], (unsigned)kv);
        }
    }
    __syncthreads();
    int base = b << BSH;
    for (int i = tid; i < (1 << BSH); i += BFIN_THR) {
        int g = base + i;
        if (g < total) {
            unsigned v = bins[i];
            out[g] = v ? rmap[NB1 - (int)(v & 0x1FFu)] : 0.0f;
        }
    }
}

// ---- Fallback path (ws too small): direct atomics + separate edges ----
__global__ __launch_bounds__(256) void k_scatter(
        const float* __restrict__ prob, const int* __restrict__ coords,
        unsigned* __restrict__ packed, int NE, int HW4, int NB1,
        const int* __restrict__ d_size1) {
    int i4 = blockIdx.x * blockDim.x + threadIdx.x;
    if (i4 * 4 >= NE) return;
    int size1 = *d_size1;
    float4 p = ((const float4*)prob)[i4];
    int4 x = ((const int4*)coords)[i4];
    int4 y = ((const int4*)(coords + NE))[i4];
    unsigned n = (unsigned)i4 / (unsigned)HW4;
    unsigned tie = (unsigned)(NB1 - (int)n);
    float pv[4] = {p.x, p.y, p.z, p.w};
    int   xv[4] = {x.x, x.y, x.z, x.w};
    int   yv[4] = {y.x, y.y, y.z, y.w};
#pragma unroll
    for (int e = 0; e < 4; ++e)
        if (pv[e] >= MASK_THR) {
            unsigned v = ((__float_as_uint(pv[e]) & 0x7FFFFFu) << 9) | tie;
            atomicMax(&packed[xv[e] * size1 + yv[e]], v);
        }
}

__global__ void k_edges(const float* __restrict__ adj, unsigned* __restrict__ deg,
                        int* __restrict__ cols, int N) {
    __shared__ unsigned lcnt;
    int r = blockIdx.x, tid = threadIdx.x;
    if (tid == 0) lcnt = 0u;
    __syncthreads();
    for (int c = tid; c < N; c += blockDim.x)
        if (adj[(size_t)r * N + c] != 0.0f) {
            unsigned pos = atomicAdd(&lcnt, 1u);
            if (pos < DEGCAP) cols[(size_t)r * DEGCAP + pos] = c;
        }
    __syncthreads();
    if (tid == 0) deg[r] = min(lcnt, (unsigned)DEGCAP);
}

__global__ void k_finalize(const unsigned* __restrict__ packed,
                           const float* __restrict__ rmap,
                           float* __restrict__ out, int total, int NB1) {
    int i4 = blockIdx.x * blockDim.x + threadIdx.x;
    if (i4 * 4 >= total) return;
    uint4 u = ((const uint4*)packed)[i4];
    unsigned v[4] = {u.x, u.y, u.z, u.w};
    float o[4];
#pragma unroll
    for (int e = 0; e < 4; ++e)
        o[e] = v[e] ? rmap[NB1 - (int)(v[e] & 0x1FFu)] : 0.0f;
    ((float4*)out)[i4] = make_float4(o[0], o[1], o[2], o[3]);
}

extern "C" void kernel_launch(void* const* d_in, const int* in_sizes, int n_in,
                              void* d_out, int out_size, void* d_ws, size_t ws_size,
                              hipStream_t stream) {
    const float* prob   = (const float*)d_in[0];
    const int*   coords = (const int*)d_in[1];
    const float* adj    = (const float*)d_in[2];
    const int*   dsz1   = (const int*)d_in[4];

    const int NE = in_sizes[0];            // 4718592
    const int NN = in_sizes[2];            // 512*512
    int N = (int)(sqrt((double)NN) + 0.5); // 512
    const int HW = NE / N;                 // 9216
    const int total = out_size;            // 1048576
    const int NB1 = N - 1;
    const int nbuck = (total + BMSK) >> BSH;   // 256

    char* ws = (char*)d_ws;
    const size_t slabB = (size_t)NBLKA * NBK * CAPB * 8;   // 33.55 MB
    const size_t ocB   = (size_t)NBLKA * 4;                // 2 KB
    const size_t ovfB  = (size_t)NBLKA * OVFC * 8;         // 256 KB
    const size_t colB  = (size_t)512 * DEGCAP * 4;         // 128 KB
    const size_t degB  = 512 * 4;
    const size_t rmapB = 512 * 4;
    const size_t needBin = slabB + ocB + ovfB + colB + degB + rmapB + 256;

    bool binOK = (nbuck <= NBK) && (N <= 512) && (N <= NBLKA) &&
                 (NE % 4 == 0) && (HW % 4 == 0) && (ws_size >= needBin);

    if (binOK) {
        size_t off = 0;
        u64* buf = (u64*)(ws + off); off += slabB;
        unsigned* ovfcnt = (unsigned*)(ws + off); off += ocB;
        u64* ovf = (u64*)(ws + off); off += ovfB;
        int* cols = (int*)(ws + off); off += colB;
        unsigned* deg = (unsigned*)(ws + off); off += degB;
        float* rmap = (float*)(ws + off);

        int NE4 = NE / 4;
        int i4PerBlk = (NE4 + NBLKA - 1) / NBLKA;
        k_binA<<<NBLKA, BLKA_THR, 0, stream>>>(
            prob, coords, adj, buf, ovfcnt, ovf, deg, cols,
            NE, HW / 4, NB1, dsz1, i4PerBlk, N);

        k_walk<<<N, 256, 0, stream>>>(deg, cols, rmap, N);

        k_binBfin<<<nbuck, BFIN_THR, 0, stream>>>(buf, ovfcnt, ovf, rmap,
                                                  (float*)d_out, total, NB1);
    } else {
        unsigned* packed = (unsigned*)ws;
        size_t off = (size_t)total * 4;
        int* cols = (int*)(ws + off); off += colB;
        unsigned* deg = (unsigned*)(ws + off); off += degB;
        float* rmap = (float*)(ws + off);

        hipMemsetAsync(packed, 0, (size_t)total * 4, stream);
        k_scatter<<<(NE / 4 + 255) / 256, 256, 0, stream>>>(
            prob, coords, packed, NE, HW / 4, NB1, dsz1);
        k_edges<<<N, 256, 0, stream>>>(adj, deg, cols, N);
        k_walk<<<N, 256, 0, stream>>>(deg, cols, rmap, N);
        k_finalize<<<(total / 4 + 255) / 256, 256, 0, stream>>>(
            packed, rmap, (float*)d_out, total, NB1);
    }
}

// Round 14
// 56.181 us; speedup vs baseline: 1.0060x; 1.0060x over previous
//
#include <hip/hip_runtime.h>
#include <math.h>

#define MASK_THR 0.53f
#define NBLKA 512       // binA blocks
#define BLKA_THR 1024   // binA threads/block (64KB slab -> 2 blk/CU)
#define BFIN_THR 1024   // binBfin threads/block
#define CAPB 32         // slots per (block,bucket) slab cell (mean fill ~17)
#define NBK 256         // max buckets
#define BSH 12          // bins per bucket = 4096
#define BMSK 4095
#define OVFC 64         // per-block overflow cap
#define DEGCAP 64       // CSR cap per node

typedef unsigned long long u64;
// native clang vectors: __builtin_nontemporal_* requires these (HIP_vector_type
// structs are rejected). Bit-identical layout to float4/int4/uint4.
typedef float    fx4 __attribute__((ext_vector_type(4)));
typedef int      ix4 __attribute__((ext_vector_type(4)));
typedef unsigned ux4 __attribute__((ext_vector_type(4)));

// ---- binA: single pass, LDS slabs, zero global atomics, fused CSR build. --
// Packing: p in [0.53,1) => exponent fixed 126 => mantissa orders as p.
// Output needs only winner's instance n => val=(mant<<9)|(NB1-n):
// max val = max p, tie -> min n.
// buf layout BUCKET-MAJOR buf[bucket][block][slot]; dump is CONDITIONAL on
// per-cell count (slots < count are all written, so no slab zero-init).
// Counts published as ushort, bucket-major, for binBfin's contiguous load.
__global__ __launch_bounds__(BLKA_THR) void k_binA(
        const float* __restrict__ prob, const int* __restrict__ coords,
        const float* __restrict__ adj,
        u64* __restrict__ buf, unsigned short* __restrict__ cnt,
        unsigned* __restrict__ ovfcnt, u64* __restrict__ ovf,
        unsigned* __restrict__ deg, int* __restrict__ cols,
        int NE, int HW4, int NB1, const int* __restrict__ d_size1,
        int i4PerBlk, int N) {
    __shared__ u64 slab[NBK * CAPB];     // 64 KB
    __shared__ unsigned hist[NBK];
    __shared__ unsigned lcnt, ocnt;
    int tid = threadIdx.x, blk = blockIdx.x;
    for (int i = tid; i < NBK; i += BLKA_THR) hist[i] = 0u;
    if (tid == 0) { lcnt = 0u; ocnt = 0u; }
    __syncthreads();
    // fused CSR build: block blk scans adjacency row blk (order-free: the
    // walk sums are exact integer fp32 adds => commutative).
    if (blk < N) {
        for (int c = tid; c < N; c += BLKA_THR)
            if (adj[(size_t)blk * N + c] != 0.0f) {
                unsigned pos = atomicAdd(&lcnt, 1u);
                if (pos < DEGCAP) cols[(size_t)blk * DEGCAP + pos] = c;
            }
    }
    // scatter into LDS slab
    int size1 = *d_size1;
    int NE4 = NE >> 2;
    int i4Base = blk * i4PerBlk;
    int i4End = min(i4Base + i4PerBlk, NE4);
    for (int i4 = i4Base + tid; i4 < i4End; i4 += BLKA_THR) {
        fx4 p = __builtin_nontemporal_load(&((const fx4*)prob)[i4]);
        float pv[4] = {p.x, p.y, p.z, p.w};
        bool any = (pv[0] >= MASK_THR) | (pv[1] >= MASK_THR) |
                   (pv[2] >= MASK_THR) | (pv[3] >= MASK_THR);
        if (!any) continue;   // skip coord loads when the whole group fails
        ix4 x = __builtin_nontemporal_load(&((const ix4*)coords)[i4]);
        ix4 y = __builtin_nontemporal_load(&((const ix4*)(coords + NE))[i4]);
        unsigned n = (unsigned)i4 / (unsigned)HW4;   // HW%4==0: 4 px share n
        unsigned tie = (unsigned)(NB1 - (int)n);
        int   xv[4] = {x.x, x.y, x.z, x.w};
        int   yv[4] = {y.x, y.y, y.z, y.w};
#pragma unroll
        for (int e = 0; e < 4; ++e)
            if (pv[e] >= MASK_THR) {
                unsigned key = (unsigned)(xv[e] * size1 + yv[e]);
                unsigned b = key >> BSH;
                unsigned v = ((__float_as_uint(pv[e]) & 0x7FFFFFu) << 9) | tie;
                unsigned pos = atomicAdd(&hist[b], 1u);
                if (pos < CAPB)
                    slab[b * CAPB + pos] = ((u64)(key & BMSK) << 32) | v;
                else {
                    unsigned g = atomicAdd(&ocnt, 1u);
                    if (g < OVFC) ovf[(size_t)blk * OVFC + g] =
                        ((u64)key << 32) | v;
                }
            }
    }
    __syncthreads();
    if (tid == 0) {
        ovfcnt[blk] = min(ocnt, (unsigned)OVFC);
        if (blk < N) deg[blk] = min(lcnt, (unsigned)DEGCAP);
    }
    // clamp, publish counts bucket-major (ushort), keep clamped in hist
    for (int b = tid; b < NBK; b += BLKA_THR) {
        unsigned c = hist[b];
        if (c > CAPB) c = CAPB;
        cnt[(size_t)b * NBLKA + blk] = (unsigned short)c;
        hist[b] = c;
    }
    __syncthreads();
    // conditional dump, bucket-major: only filled slots
    for (int j = tid; j < NBK * CAPB; j += BLKA_THR) {
        int b = j >> 5, s = j & (CAPB - 1);
        if (s < (int)hist[b])
            __builtin_nontemporal_store(
                slab[j], &buf[((size_t)b * NBLKA + blk) * CAPB + s]);
    }
}

// ---- k_walk: one block per node. v <- (I+A) v, 10 times, in LDS; then
// remap[i] = 1 + max({i} U {j != i : v[j] > 1}). Exactness: all counts are
// nonneg integers; 0/1 entries are sums of tiny exact terms (exact in fp32
// in both this and the reference's matmuls); entries >= 2 can round but
// never below the >1 threshold => classification identical to reference. ----
__global__ __launch_bounds__(256) void k_walk(
        const unsigned* __restrict__ deg, const int* __restrict__ cols,
        float* __restrict__ rmap, int N) {
    __shared__ float v0[512], v1[512];
    __shared__ int red[4];
    int i = blockIdx.x, tid = threadIdx.x;
    for (int j = tid; j < N; j += 256) v0[j] = (j == i) ? 1.0f : 0.0f;
    __syncthreads();
    float* cur = v0; float* nxt = v1;
    for (int it = 0; it < 10; ++it) {
        for (int j = tid; j < N; j += 256) {
            float s = cur[j];
            unsigned d = deg[j];
            const int* cj = cols + (size_t)j * DEGCAP;
            for (unsigned k = 0; k < d; ++k) s += cur[cj[k]];
            nxt[j] = s;
        }
        __syncthreads();
        float* t = cur; cur = nxt; nxt = t;
    }
    int best = i;
    for (int j = tid; j < N; j += 256)
        if (j != i && cur[j] > 1.0f && j > best) best = j;
    for (int off = 32; off; off >>= 1) {
        int o = __shfl_down(best, off);
        if (o > best) best = o;
    }
    if ((tid & 63) == 0) red[tid >> 6] = best;
    __syncthreads();
    if (tid == 0) {
        for (int w = 1; w < 4; ++w) if (red[w] > best) best = red[w];
        rmap[i] = (float)(best + 1);
    }
}

// ---- binBfin: block b loads its 512 counts (contiguous ushort), streams the
// filled prefix of each 256B segment (guarded uint4 pairs; stale slots never
// touched), LDS-atomicMax merge, then overflow, then writes the output
// segment [b<<BSH,(b+1)<<BSH) through rmap. ----
__global__ __launch_bounds__(BFIN_THR) void k_binBfin(
        const u64* __restrict__ buf, const unsigned short* __restrict__ cnt,
        const unsigned* __restrict__ ovfcnt, const u64* __restrict__ ovf,
        const float* __restrict__ rmap, float* __restrict__ out,
        int total, int NB1) {
    __shared__ unsigned bins[1 << BSH];     // 16 KB
    __shared__ unsigned short lc[NBLKA];    // 1 KB
    __shared__ unsigned oc[NBLKA];          // 2 KB
    int b = blockIdx.x, tid = threadIdx.x;
    for (int i = tid; i < (1 << BSH); i += BFIN_THR) bins[i] = 0u;
    for (int s = tid; s < NBLKA; s += BFIN_THR) {
        lc[s] = cnt[(size_t)b * NBLKA + s];
        oc[s] = ovfcnt[s];
    }
    __syncthreads();
    const int W = CAPB / 2;   // uint4 slots per segment
    const ux4* base = (const ux4*)(buf + (size_t)b * NBLKA * CAPB);
    for (int j = tid; j < NBLKA * W; j += BFIN_THR) {
        int s = j / W, w = j % W;
        int c = (int)lc[s];
        if (2 * w < c) {
            ux4 u = __builtin_nontemporal_load(&base[s * W + w]);
            atomicMax(&bins[u.y], u.x);   // key=high dword, val=low
            if (2 * w + 1 < c) atomicMax(&bins[u.w], u.z);
        }
    }
    for (int j = tid; j < NBLKA * OVFC; j += BFIN_THR) {
        int s = j / OVFC, e = j % OVFC;
        if (e < (int)oc[s]) {
            u64 kv = ovf[(size_t)s * OVFC + e];
            unsigned key = (unsigned)(kv >> 32);
            if ((int)(key >> BSH) == b)
                atomicMax(&bins[key & BMSK], (unsigned)kv);
        }
    }
    __syncthreads();
    int bse = b << BSH;
    for (int i = tid; i < (1 << BSH); i += BFIN_THR) {
        int g = bse + i;
        if (g < total) {
            unsigned v = bins[i];
            float o = v ? rmap[NB1 - (int)(v & 0x1FFu)] : 0.0f;
            __builtin_nontemporal_store(o, &out[g]);
        }
    }
}

// ---- Fallback path (ws too small): direct atomics + separate edges ----
__global__ __launch_bounds__(256) void k_scatter(
        const float* __restrict__ prob, const int* __restrict__ coords,
        unsigned* __restrict__ packed, int NE, int HW4, int NB1,
        const int* __restrict__ d_size1) {
    int i4 = blockIdx.x * blockDim.x + threadIdx.x;
    if (i4 * 4 >= NE) return;
    int size1 = *d_size1;
    float4 p = ((const float4*)prob)[i4];
    int4 x = ((const int4*)coords)[i4];
    int4 y = ((const int4*)(coords + NE))[i4];
    unsigned n = (unsigned)i4 / (unsigned)HW4;
    unsigned tie = (unsigned)(NB1 - (int)n);
    float pv[4] = {p.x, p.y, p.z, p.w};
    int   xv[4] = {x.x, x.y, x.z, x.w};
    int   yv[4] = {y.x, y.y, y.z, y.w};
#pragma unroll
    for (int e = 0; e < 4; ++e)
        if (pv[e] >= MASK_THR) {
            unsigned v = ((__float_as_uint(pv[e]) & 0x7FFFFFu) << 9) | tie;
            atomicMax(&packed[xv[e] * size1 + yv[e]], v);
        }
}

__global__ void k_edges(const float* __restrict__ adj, unsigned* __restrict__ deg,
                        int* __restrict__ cols, int N) {
    __shared__ unsigned lcnt;
    int r = blockIdx.x, tid = threadIdx.x;
    if (tid == 0) lcnt = 0u;
    __syncthreads();
    for (int c = tid; c < N; c += blockDim.x)
        if (adj[(size_t)r * N + c] != 0.0f) {
            unsigned pos = atomicAdd(&lcnt, 1u);
            if (pos < DEGCAP) cols[(size_t)r * DEGCAP + pos] = c;
        }
    __syncthreads();
    if (tid == 0) deg[r] = min(lcnt, (unsigned)DEGCAP);
}

__global__ void k_finalize(const unsigned* __restrict__ packed,
                           const float* __restrict__ rmap,
                           float* __restrict__ out, int total, int NB1) {
    int i4 = blockIdx.x * blockDim.x + threadIdx.x;
    if (i4 * 4 >= total) return;
    uint4 u = ((const uint4*)packed)[i4];
    unsigned v[4] = {u.x, u.y, u.z, u.w};
    float o[4];
#pragma unroll
    for (int e = 0; e < 4; ++e)
        o[e] = v[e] ? rmap[NB1 - (int)(v[e] & 0x1FFu)] : 0.0f;
    ((float4*)out)[i4] = make_float4(o[0], o[1], o[2], o[3]);
}

extern "C" void kernel_launch(void* const* d_in, const int* in_sizes, int n_in,
                              void* d_out, int out_size, void* d_ws, size_t ws_size,
                              hipStream_t stream) {
    const float* prob   = (const float*)d_in[0];
    const int*   coords = (const int*)d_in[1];
    const float* adj    = (const float*)d_in[2];
    const int*   dsz1   = (const int*)d_in[4];

    const int NE = in_sizes[0];            // 4718592
    const int NN = in_sizes[2];            // 512*512
    int N = (int)(sqrt((double)NN) + 0.5); // 512
    const int HW = NE / N;                 // 9216
    const int total = out_size;            // 1048576
    const int NB1 = N - 1;
    const int nbuck = (total + BMSK) >> BSH;   // 256

    char* ws = (char*)d_ws;
    const size_t slabB = (size_t)NBLKA * NBK * CAPB * 8;   // 33.55 MB
    const size_t cntB  = (size_t)NBK * NBLKA * 2;          // 256 KB
    const size_t ocB   = (size_t)NBLKA * 4;                // 2 KB
    const size_t ovfB  = (size_t)NBLKA * OVFC * 8;         // 256 KB
    const size_t colB  = (size_t)512 * DEGCAP * 4;         // 128 KB
    const size_t degB  = 512 * 4;
    const size_t rmapB = 512 * 4;
    const size_t needBin = slabB + cntB + ocB + ovfB + colB + degB + rmapB + 256;

    bool binOK = (nbuck <= NBK) && (N <= 512) && (N <= NBLKA) &&
                 (NE % 4 == 0) && (HW % 4 == 0) && (ws_size >= needBin);

    if (binOK) {
        size_t off = 0;
        u64* buf = (u64*)(ws + off); off += slabB;
        unsigned short* cnt = (unsigned short*)(ws + off); off += cntB;
        unsigned* ovfcnt = (unsigned*)(ws + off); off += ocB;
        u64* ovf = (u64*)(ws + off); off += ovfB;
        int* cols = (int*)(ws + off); off += colB;
        unsigned* deg = (unsigned*)(ws + off); off += degB;
        float* rmap = (float*)(ws + off);

        int NE4 = NE / 4;
        int i4PerBlk = (NE4 + NBLKA - 1) / NBLKA;
        k_binA<<<NBLKA, BLKA_THR, 0, stream>>>(
            prob, coords, adj, buf, cnt, ovfcnt, ovf, deg, cols,
            NE, HW / 4, NB1, dsz1, i4PerBlk, N);

        k_walk<<<N, 256, 0, stream>>>(deg, cols, rmap, N);

        k_binBfin<<<nbuck, BFIN_THR, 0, stream>>>(buf, cnt, ovfcnt, ovf, rmap,
                                                  (float*)d_out, total, NB1);
    } else {
        unsigned* packed = (unsigned*)ws;
        size_t off = (size_t)total * 4;
        int* cols = (int*)(ws + off); off += colB;
        unsigned* deg = (unsigned*)(ws + off); off += degB;
        float* rmap = (float*)(ws + off);

        (void)hipMemsetAsync(packed, 0, (size_t)total * 4, stream);
        k_scatter<<<(NE / 4 + 255) / 256, 256, 0, stream>>>(
            prob, coords, packed, NE, HW / 4, NB1, dsz1);
        k_edges<<<N, 256, 0, stream>>>(adj, deg, cols, N);
        k_walk<<<N, 256, 0, stream>>>(deg, cols, rmap, N);
        k_finalize<<<(total / 4 + 255) / 256, 256, 0, stream>>>(
            packed, rmap, (float*)d_out, total, NB1);
    }
}